// Round 7
// baseline (34228.796 us; speedup 1.0000x reference)
//
#include <hip/hip_runtime.h>
#include <hip/hip_bf16.h>

// ============================================================================
// Seq2seq: bi-GRU encoder (T=8192, H=I=1024) + attention decoder (L=64).
// Inputs/outputs are fp32 (proven, absmax 0.0625).
//  - gi = x@Wih.T batched into one GEMM (8192x1024 @ 1024x6144), bf16 scratch.
//  - attention softmax shift-invariance => attn/context constant across all 64
//    decoder steps; computed once.
//  - recurrence sync (r0-proven, UNCHANGED here): each h element published as
//    an 8B word [epoch32|fp32]; arrival = one relaxed agent store, detection =
//    1 word/thread polled (s_sleep(1) spin) for epoch==t. Double-buffered by
//    parity; all-to-all reads make exact-match polling race-free.
//  - sync design space is exhausted: r1 backoff+packing SLOWER, r3 striding
//    MUCH slower, r4/r5 XCD-local never visible, r6 pipelined poll SLOWER
//    (dangling speculative load drained by vmcnt(0) at the barrier = +1 RTT).
//  - THIS ROUND attacks the COMPUTE phase: the old dot loop issued ~192
//    ds_read_b128/block/step (~1500-2300cy serialized LDS occupancy on the
//    critical path). Now Whh lives in REGISTERS (wave w<8 holds the 3 rows of
//    output j0+w, 48 VGPRs, exact fp32); dot = 4 LDS b128 h-reads + 48 FMAs;
//    in-wave butterfly reduce; lane 0 does gates (__expf) + publish. One
//    barrier/step (hsh parity-double-buffered; race-freedom argued inline).
//    Waves 8-15 are dedicated pollers.
// ============================================================================
typedef __hip_bfloat16 bf16_t;
typedef unsigned long long u64;
struct alignas(8) bh4 { bf16_t v[4]; };
__device__ __forceinline__ float bf2f(bf16_t v) { return __bfloat162float(v); }

// workspace offsets (floats); total ~168 MB (r0-proven in-bounds)
static constexpr size_t OFF_ENC2   = 25165824;                 // after bf16 GI
static constexpr size_t OFF_SCORES = OFF_ENC2 + 16777216;
static constexpr size_t OFF_CTX    = OFF_SCORES + 8192;
static constexpr size_t OFF_GICTX  = OFF_CTX + 2048;           // 3072 (+pad)
static constexpr size_t OFF_PUB    = OFF_GICTX + 4096;         // u64 region
// u64 region: pub_f[2][1024] | pub_b[2][1024] | hpub[2][1024] | lpub[2][2048]

static constexpr unsigned TAG_BAD = 0x7FFFFFFFu;

__device__ __forceinline__ u64 pub_load(const u64* p) {
  return __hip_atomic_load(p, __ATOMIC_RELAXED, __HIP_MEMORY_SCOPE_AGENT);
}
__device__ __forceinline__ void pub_store(u64* p, u64 v) {
  __hip_atomic_store(p, v, __ATOMIC_RELAXED, __HIP_MEMORY_SCOPE_AGENT);
}
__device__ __forceinline__ u64 pack(unsigned tag, float f) {
  union { float f; unsigned u; } c; c.f = f;
  return ((u64)tag << 32) | c.u;
}
__device__ __forceinline__ float unpack(u64 w) {
  union { unsigned u; float f; } c; c.u = (unsigned)w;
  return c.f;
}
// fast gate math (few-ulp; error budget dominated by bf16 GI scratch; passed r6)
__device__ __forceinline__ float fsigmoid(float x) {
  return 1.f / (1.f + __expf(-x));
}
__device__ __forceinline__ float ftanh(float x) {
  float e2 = __expf(2.f * x);
  return 1.f - 2.f / (e2 + 1.f);
}

// ----------------------------------------------------------------------------
__global__ __launch_bounds__(1024) void k_init(const float* __restrict__ h0,
                                               u64* pub) {
  int i = blockIdx.x * 1024 + threadIdx.x;  // grid 10 -> 10240 words
  if (i < 1024)       pub[i] = pack(0u, h0[i]);                 // pub_f[0]
  else if (i < 2048)  pub[i] = pack(TAG_BAD, 0.f);              // pub_f[1]
  else if (i < 3072)  pub[i] = pack(0u, h0[1024 + (i - 2048)]); // pub_b[0]
  else if (i < 10240) pub[i] = pack(TAG_BAD, 0.f);              // rest
}

// ----------------------------------------------------------------------------
// GI = X @ [Wih_f; Wih_b]^T + bias.  64x64 tile, 4x4 microtile, fp32 math,
// bf16 store (scratch only).  (proven, unchanged)
// ----------------------------------------------------------------------------
__global__ __launch_bounds__(256) void k_gemm_gi(
    const float* __restrict__ X, const float* __restrict__ Wf,
    const float* __restrict__ Wb, const float* __restrict__ bf,
    const float* __restrict__ bb, bf16_t* __restrict__ GI) {
  __shared__ __align__(16) float As[16][68];
  __shared__ __align__(16) float Bs[16][68];
  const int m0 = blockIdx.x * 64;
  const int n0 = blockIdx.y * 64;
  const int tid = threadIdx.x;
  const int tx = tid & 15, ty = tid >> 4;
  const int lm = tid >> 2, lk = (tid & 3) * 4;
  const float* Wsel = (n0 < 3072) ? Wf : Wb;
  const float* bsel = (n0 < 3072) ? bf : bb;
  const int nadj = (n0 < 3072) ? n0 : (n0 - 3072);
  float acc[4][4];
#pragma unroll
  for (int i = 0; i < 4; ++i)
#pragma unroll
    for (int j = 0; j < 4; ++j) acc[i][j] = 0.f;
  for (int k0 = 0; k0 < 1024; k0 += 16) {
    float4 av = *(const float4*)(X + (size_t)(m0 + lm) * 1024 + k0 + lk);
    float4 bv = *(const float4*)(Wsel + (size_t)(nadj + lm) * 1024 + k0 + lk);
    __syncthreads();
    As[lk + 0][lm] = av.x; As[lk + 1][lm] = av.y; As[lk + 2][lm] = av.z; As[lk + 3][lm] = av.w;
    Bs[lk + 0][lm] = bv.x; Bs[lk + 1][lm] = bv.y; Bs[lk + 2][lm] = bv.z; Bs[lk + 3][lm] = bv.w;
    __syncthreads();
#pragma unroll
    for (int kk = 0; kk < 16; ++kk) {
      float4 a = *(const float4*)&As[kk][ty * 4];
      float4 b = *(const float4*)&Bs[kk][tx * 4];
      acc[0][0] += a.x * b.x; acc[0][1] += a.x * b.y; acc[0][2] += a.x * b.z; acc[0][3] += a.x * b.w;
      acc[1][0] += a.y * b.x; acc[1][1] += a.y * b.y; acc[1][2] += a.y * b.z; acc[1][3] += a.y * b.w;
      acc[2][0] += a.z * b.x; acc[2][1] += a.z * b.y; acc[2][2] += a.z * b.z; acc[2][3] += a.z * b.w;
      acc[3][0] += a.w * b.x; acc[3][1] += a.w * b.y; acc[3][2] += a.w * b.z; acc[3][3] += a.w * b.w;
    }
  }
  float b0 = bsel[nadj + tx * 4 + 0], b1 = bsel[nadj + tx * 4 + 1];
  float b2 = bsel[nadj + tx * 4 + 2], b3 = bsel[nadj + tx * 4 + 3];
#pragma unroll
  for (int i = 0; i < 4; ++i) {
    bh4 o;
    o.v[0] = __float2bfloat16(acc[i][0] + b0);
    o.v[1] = __float2bfloat16(acc[i][1] + b1);
    o.v[2] = __float2bfloat16(acc[i][2] + b2);
    o.v[3] = __float2bfloat16(acc[i][3] + b3);
    *(bh4*)(GI + (size_t)(m0 + ty * 4 + i) * 6144 + n0 + tx * 4) = o;
  }
}

// ----------------------------------------------------------------------------
// Both GRU recurrences. 256 blocks x 1024 thr; 100KB LDS pad -> 1 block/CU.
// Wave w<8 holds the 3 Whh rows of output j0+w in 48 VGPRs (exact fp32).
// Per step: all threads poll own word (r0 spin) -> write hsh[parity] -> ONE
// barrier -> waves 0-7: 4 LDS b128 h-reads + 48 reg-FMAs, butterfly reduce,
// lane 0 gates (__expf) + publish + enc2 + gi prefetch. Waves 8-15 poll only.
// Race-freedom of the single barrier: polls of t+1 write parity (t+1)&1
// (disjoint from dots of t reading parity t&1); polls of t+2 (parity t&1)
// are ordered after sync(t+1), which is after all dots(t)/gate-reads(t);
// own-word overwrite is gated by our own publish (data dependence) — r0 arg.
// ----------------------------------------------------------------------------
__global__ __launch_bounds__(1024, 1) void k_recurrence(
    const bf16_t* __restrict__ GI, const float* __restrict__ Whh_f,
    const float* __restrict__ Whh_b, const float* __restrict__ bhh_f,
    const float* __restrict__ bhh_b, float* __restrict__ enc2,
    u64* pub_f, u64* pub_b) {
  __shared__ __align__(16) float smem[25600];  // 100KB: hsh[2][1024] + pad
  float* hsh0 = smem;
  float* hsh1 = smem + 1024;
  const int blk = blockIdx.x;      // 0..255
  const int dir = blk >> 7;        // 128 blocks/direction
  const int bb = blk & 127;
  const int j0 = bb * 8;
  const int tid = threadIdx.x;
  const int wv = tid >> 6, lane = tid & 63;
  const float* Whh = dir ? Whh_b : Whh_f;
  const float* bhh = dir ? bhh_b : bhh_f;
  u64* pub = dir ? pub_b : pub_f;

  // Whh rows of output j0+wv into registers: 3 rows x 4 float4 = 48 VGPRs.
  float4 wr0[4], wr1[4], wr2[4];
  float br = 0.f, bz = 0.f, bn = 0.f;
  float gir = 0.f, giz = 0.f, gin = 0.f;
  size_t gbase = 0;
  if (wv < 8) {
    int j = j0 + wv;
    const float* r0p = Whh + (size_t)(0 * 1024 + j) * 1024;
    const float* r1p = Whh + (size_t)(1 * 1024 + j) * 1024;
    const float* r2p = Whh + (size_t)(2 * 1024 + j) * 1024;
#pragma unroll
    for (int q = 0; q < 4; ++q) {
      wr0[q] = *(const float4*)(r0p + 4 * lane + 256 * q);
      wr1[q] = *(const float4*)(r1p + 4 * lane + 256 * q);
      wr2[q] = *(const float4*)(r2p + 4 * lane + 256 * q);
    }
    br = bhh[j]; bz = bhh[1024 + j]; bn = bhh[2048 + j];
    gbase = (size_t)(dir ? 3072 : 0) + j;
    size_t row0 = dir ? (size_t)8191 : (size_t)0;
    gir = bf2f(GI[row0 * 6144 + gbase]);
    giz = bf2f(GI[row0 * 6144 + gbase + 1024]);
    gin = bf2f(GI[row0 * 6144 + gbase + 2048]);
  }

  for (int t = 0; t < 8192; ++t) {
    float* hcur = (t & 1) ? hsh1 : hsh0;
    {  // r0-proven poll: hot spin + s_sleep(1), 1 word/thread
      u64* src = pub + (size_t)(t & 1) * 1024 + tid;
      u64 wd = pub_load(src);
      while ((unsigned)(wd >> 32) != (unsigned)t) {
        __builtin_amdgcn_s_sleep(1);
        wd = pub_load(src);
      }
      hcur[tid] = unpack(wd);
    }
    __syncthreads();                 // the only barrier per step
    if (wv < 8) {
      const float4* hp = (const float4*)hcur;
      float ar = 0.f, az = 0.f, an = 0.f;
#pragma unroll
      for (int q = 0; q < 4; ++q) {
        float4 hv = hp[lane + 64 * q];
        ar += hv.x * wr0[q].x + hv.y * wr0[q].y + hv.z * wr0[q].z + hv.w * wr0[q].w;
        az += hv.x * wr1[q].x + hv.y * wr1[q].y + hv.z * wr1[q].z + hv.w * wr1[q].w;
        an += hv.x * wr2[q].x + hv.y * wr2[q].y + hv.z * wr2[q].z + hv.w * wr2[q].w;
      }
#pragma unroll
      for (int off = 32; off; off >>= 1) {
        ar += __shfl_xor(ar, off);
        az += __shfl_xor(az, off);
        an += __shfl_xor(an, off);
      }
      if (lane == 0) {
        int j = j0 + wv;
        float rr = fsigmoid(gir + ar + br);
        float zz = fsigmoid(giz + az + bz);
        float nn = ftanh(gin + rr * (an + bn));
        float hnew = (1.f - zz) * nn + zz * hcur[j];
        pub_store(pub + (size_t)((t + 1) & 1) * 1024 + j,
                  pack((unsigned)(t + 1), hnew));
        size_t trow = dir ? (size_t)(8191 - t) : (size_t)t;
        enc2[trow * 2048 + dir * 1024 + j] = hnew;
        if (t < 8191) {              // prefetch next gi (hidden by next poll)
          size_t row = dir ? (size_t)(8190 - t) : (size_t)(t + 1);
          gir = bf2f(GI[row * 6144 + gbase]);
          giz = bf2f(GI[row * 6144 + gbase + 1024]);
          gin = bf2f(GI[row * 6144 + gbase + 2048]);
        }
      }
    }
  }
}

// ----------------------------------------------------------------------------
__global__ __launch_bounds__(256) void k_scores(const float* __restrict__ enc2,
                                                const float* __restrict__ Watt,
                                                const float* __restrict__ batt,
                                                float* __restrict__ scores) {
  int wv = threadIdx.x >> 6, lane = threadIdx.x & 63;
  int t = blockIdx.x * 4 + wv;  // grid 2048
  const float* We = Watt + 1024;
  float a = 0.f;
#pragma unroll
  for (int k = 0; k < 8; ++k) {
    float4 e = *(const float4*)(enc2 + (size_t)t * 2048 + lane * 4 + k * 256);
    float4 ww = *(const float4*)(We + lane * 4 + k * 256);
    a += e.x * ww.x + e.y * ww.y + e.z * ww.z + e.w * ww.w;
  }
#pragma unroll
  for (int off = 32; off; off >>= 1) a += __shfl_xor(a, off);
  if (lane == 0) scores[t] = a + batt[0];
}

__global__ __launch_bounds__(256) void k_softmax(float* __restrict__ s) {
  __shared__ float red[8];
  int tid = threadIdx.x, wv = tid >> 6, lane = tid & 63;
  float m = -1e30f;
  for (int i = tid; i < 8192; i += 256) m = fmaxf(m, s[i]);
#pragma unroll
  for (int off = 32; off; off >>= 1) m = fmaxf(m, __shfl_xor(m, off));
  if (lane == 0) red[wv] = m;
  __syncthreads();
  m = fmaxf(fmaxf(red[0], red[1]), fmaxf(red[2], red[3]));
  float sum = 0.f;
  for (int i = tid; i < 8192; i += 256) sum += expf(s[i] - m);
#pragma unroll
  for (int off = 32; off; off >>= 1) sum += __shfl_xor(sum, off);
  if (lane == 0) red[4 + wv] = sum;
  __syncthreads();
  sum = red[4] + red[5] + red[6] + red[7];
  float inv = 1.0f / sum;
  for (int i = tid; i < 8192; i += 256) s[i] = expf(s[i] - m) * inv;
}

__global__ __launch_bounds__(256) void k_context(const float* __restrict__ attn,
                                                 const float* __restrict__ enc2,
                                                 float* __restrict__ ctx) {
  int k = blockIdx.x * 256 + threadIdx.x;  // grid 8
  float a0 = 0.f, a1 = 0.f, a2 = 0.f, a3 = 0.f;
  for (int t = 0; t < 8192; t += 4) {
    a0 += attn[t] * enc2[(size_t)t * 2048 + k];
    a1 += attn[t + 1] * enc2[(size_t)(t + 1) * 2048 + k];
    a2 += attn[t + 2] * enc2[(size_t)(t + 2) * 2048 + k];
    a3 += attn[t + 3] * enc2[(size_t)(t + 3) * 2048 + k];
  }
  ctx[k] = (a0 + a1) + (a2 + a3);
}

__global__ __launch_bounds__(256) void k_gictx(const float* __restrict__ dWih,
                                               const float* __restrict__ dbih,
                                               const float* __restrict__ ctx,
                                               float* __restrict__ gictx) {
  int wv = threadIdx.x >> 6, lane = threadIdx.x & 63;
  int i = blockIdx.x * 4 + wv;  // grid 768 -> 3072
  float a = 0.f;
#pragma unroll
  for (int k = 0; k < 8; ++k) {
    float4 ww = *(const float4*)(dWih + (size_t)i * 4096 + 2048 + lane * 4 + k * 256);
    float4 c = *(const float4*)(ctx + lane * 4 + k * 256);
    a += ww.x * c.x + ww.y * c.y + ww.z * c.z + ww.w * c.w;
  }
#pragma unroll
  for (int off = 32; off; off >>= 1) a += __shfl_xor(a, off);
  if (lane == 0) gictx[i] = a + dbih[i];
}

// seed decoder h state (tag 0) from bwd final h (tag 8192, parity 0)
__global__ void k_decinit(const u64* __restrict__ pub_b, u64* hpub) {
  int i = threadIdx.x;  // 1x1024
  hpub[i] = pack(0u, unpack(pub_b[i]));
}

// ----------------------------------------------------------------------------
// Decoder: 64 steps, 128 blocks x 1024 thr (r0-proven, unchanged).
// ----------------------------------------------------------------------------
__global__ __launch_bounds__(1024, 1) void k_decoder(
    const float* __restrict__ gictx, const float* __restrict__ dWih,
    const float* __restrict__ dWhh, const float* __restrict__ dbhh,
    const float* __restrict__ Wout, const float* __restrict__ bout,
    u64* hpub, u64* lpub, float* __restrict__ out) {
  __shared__ __align__(16) float hsh[1024];
  __shared__ __align__(16) float lsh[2048];
  __shared__ __align__(16) float dsh[2048];
  __shared__ float rsA[24], rsB[24];
  __shared__ float red[32];
  __shared__ float gctx[24], bsh[24], bo[16];
  const int bb = blockIdx.x;           // 128 blocks
  const int j0 = bb * 8, o0 = bb * 16;
  const int tid = threadIdx.x, wv = tid >> 6, lane = tid & 63;
  if (tid < 24) {
    int g = tid >> 3, jj = tid & 7;
    gctx[tid] = gictx[g * 1024 + j0 + jj];
    bsh[tid] = dbhh[g * 1024 + j0 + jj];
  }
  if (tid < 16) bo[tid] = bout[o0 + tid];
  __syncthreads();

  for (int s = 0; s < 64; ++s) {
    {  // poll h state (tag s)
      u64* hp = hpub + (size_t)(s & 1) * 1024 + tid;
      u64 wd = pub_load(hp);
      while ((unsigned)(wd >> 32) != (unsigned)s) {
        __builtin_amdgcn_s_sleep(1);
        wd = pub_load(hp);
      }
      hsh[tid] = unpack(wd);
    }
    if (s > 0) {  // poll logits (tag s)
      u64* lp = lpub + (size_t)(s & 1) * 2048;
#pragma unroll
      for (int q = 0; q < 2; ++q) {
        int i = tid + q * 1024;
        u64 wd = pub_load(lp + i);
        while ((unsigned)(wd >> 32) != (unsigned)s) {
          __builtin_amdgcn_s_sleep(1);
          wd = pub_load(lp + i);
        }
        lsh[i] = unpack(wd);
      }
    }
    __syncthreads();
    if (s > 0) {  // log-softmax over lsh (redundant per block, deterministic)
      float m = fmaxf(lsh[tid], lsh[tid + 1024]);
#pragma unroll
      for (int off = 32; off; off >>= 1) m = fmaxf(m, __shfl_xor(m, off));
      if (lane == 0) red[wv] = m;
      __syncthreads();
      m = -1e30f;
      for (int i = 0; i < 16; ++i) m = fmaxf(m, red[i]);
      float e = expf(lsh[tid] - m) + expf(lsh[tid + 1024] - m);
#pragma unroll
      for (int off = 32; off; off >>= 1) e += __shfl_xor(e, off);
      if (lane == 0) red[16 + wv] = e;
      __syncthreads();
      float se = 0.f;
      for (int i = 0; i < 16; ++i) se += red[16 + i];
      float c = m + logf(se);
      dsh[tid] = lsh[tid] - c;
      dsh[tid + 1024] = lsh[tid + 1024] - c;
    } else {
      dsh[tid] = 0.f;
      dsh[tid + 1024] = 0.f;
    }
    __syncthreads();
    if (s > 0 && tid < 16) out[(size_t)(s - 1) * 2048 + o0 + tid] = dsh[o0 + tid];
    // gate dots: combo r = g*8+jj; wave wv -> combo wv (+16+wv if wv<8)
    float aA0 = 0.f, aB0 = 0.f, aA1 = 0.f, aB1 = 0.f;
    {
      int g = wv >> 3, jj = wv & 7;
      const float4* rowI = (const float4*)(dWih + (size_t)(g * 1024 + j0 + jj) * 4096);
      const float4* rowH = (const float4*)(dWhh + (size_t)(g * 1024 + j0 + jj) * 1024);
      const float4* dp = (const float4*)dsh;
      const float4* hp = (const float4*)hsh;
#pragma unroll
      for (int q = 0; q < 8; ++q) {
        int idx = lane + 64 * q;
        float4 d = dp[idx], wi = rowI[idx];
        aA0 += d.x * wi.x + d.y * wi.y + d.z * wi.z + d.w * wi.w;
      }
#pragma unroll
      for (int q = 0; q < 4; ++q) {
        int idx = lane + 64 * q;
        float4 h = hp[idx], wh = rowH[idx];
        aB0 += h.x * wh.x + h.y * wh.y + h.z * wh.z + h.w * wh.w;
      }
      if (wv < 8) {
        const float4* rowI2 = (const float4*)(dWih + (size_t)(2 * 1024 + j0 + wv) * 4096);
        const float4* rowH2 = (const float4*)(dWhh + (size_t)(2 * 1024 + j0 + wv) * 1024);
#pragma unroll
        for (int q = 0; q < 8; ++q) {
          int idx = lane + 64 * q;
          float4 d = dp[idx], wi = rowI2[idx];
          aA1 += d.x * wi.x + d.y * wi.y + d.z * wi.z + d.w * wi.w;
        }
#pragma unroll
        for (int q = 0; q < 4; ++q) {
          int idx = lane + 64 * q;
          float4 h = hp[idx], wh = rowH2[idx];
          aB1 += h.x * wh.x + h.y * wh.y + h.z * wh.z + h.w * wh.w;
        }
      }
    }
#pragma unroll
    for (int off = 32; off; off >>= 1) {
      aA0 += __shfl_xor(aA0, off); aB0 += __shfl_xor(aB0, off);
      aA1 += __shfl_xor(aA1, off); aB1 += __shfl_xor(aB1, off);
    }
    if (lane == 0) {
      rsA[wv] = aA0; rsB[wv] = aB0;
      if (wv < 8) { rsA[16 + wv] = aA1; rsB[16 + wv] = aB1; }
    }
    __syncthreads();
    if (tid < 8) {
      int jj = tid, j = j0 + jj;
      float ir = gctx[jj] + rsA[jj];
      float iz = gctx[8 + jj] + rsA[8 + jj];
      float inn = gctx[16 + jj] + rsA[16 + jj];
      float hr = rsB[jj] + bsh[jj];
      float hz = rsB[8 + jj] + bsh[8 + jj];
      float hn = rsB[16 + jj] + bsh[16 + jj];
      float rr = 1.f / (1.f + expf(-(ir + hr)));
      float zz = 1.f / (1.f + expf(-(iz + hz)));
      float nn = tanhf(inn + rr * hn);
      float hnew = (1.f - zz) * nn + zz * hsh[j];
      pub_store(hpub + (size_t)((s + 1) & 1) * 1024 + j, pack((unsigned)(s + 1), hnew));
    }
    __syncthreads();
    {  // phase B: poll h(tag s+1), compute 16 logit rows, publish
      u64* hp = hpub + (size_t)((s + 1) & 1) * 1024 + tid;
      u64 wd = pub_load(hp);
      while ((unsigned)(wd >> 32) != (unsigned)(s + 1)) {
        __builtin_amdgcn_s_sleep(1);
        wd = pub_load(hp);
      }
      hsh[tid] = unpack(wd);
    }
    __syncthreads();
    {
      int o = o0 + wv;
      const float4* rowO = (const float4*)(Wout + (size_t)o * 1024);
      const float4* hp = (const float4*)hsh;
      float l = 0.f;
#pragma unroll
      for (int q = 0; q < 4; ++q) {
        int idx = lane + 64 * q;
        float4 h = hp[idx], wo = rowO[idx];
        l += h.x * wo.x + h.y * wo.y + h.z * wo.z + h.w * wo.w;
      }
#pragma unroll
      for (int off = 32; off; off >>= 1) l += __shfl_xor(l, off);
      if (lane == 0)
        pub_store(lpub + (size_t)((s + 1) & 1) * 2048 + o, pack((unsigned)(s + 1), l + bo[wv]));
    }
    __syncthreads();
  }
  {  // final: logits tag 64 (parity 0) -> out step 63
    u64* lp = lpub + 0;
#pragma unroll
    for (int q = 0; q < 2; ++q) {
      int i = tid + q * 1024;
      u64 wd = pub_load(lp + i);
      while ((unsigned)(wd >> 32) != 64u) {
        __builtin_amdgcn_s_sleep(1);
        wd = pub_load(lp + i);
      }
      lsh[i] = unpack(wd);
    }
  }
  __syncthreads();
  float m = fmaxf(lsh[tid], lsh[tid + 1024]);
#pragma unroll
  for (int off = 32; off; off >>= 1) m = fmaxf(m, __shfl_xor(m, off));
  if (lane == 0) red[wv] = m;
  __syncthreads();
  m = -1e30f;
  for (int i = 0; i < 16; ++i) m = fmaxf(m, red[i]);
  float e = expf(lsh[tid] - m) + expf(lsh[tid + 1024] - m);
#pragma unroll
  for (int off = 32; off; off >>= 1) e += __shfl_xor(e, off);
  if (lane == 0) red[16 + wv] = e;
  __syncthreads();
  float se = 0.f;
  for (int i = 0; i < 16; ++i) se += red[16 + i];
  float c = m + logf(se);
  if (tid < 16) out[(size_t)63 * 2048 + o0 + tid] = lsh[o0 + tid] - c;
}

// ----------------------------------------------------------------------------
extern "C" void kernel_launch(void* const* d_in, const int* in_sizes, int n_in,
                              void* d_out, int out_size, void* d_ws, size_t ws_size,
                              hipStream_t stream) {
  (void)in_sizes; (void)n_in; (void)out_size; (void)ws_size;
  const float* x      = (const float*)d_in[0];
  const float* h0     = (const float*)d_in[1];
  const float* eWih_f = (const float*)d_in[2];
  const float* eWhh_f = (const float*)d_in[3];
  const float* ebih_f = (const float*)d_in[4];
  const float* ebhh_f = (const float*)d_in[5];
  const float* eWih_b = (const float*)d_in[6];
  const float* eWhh_b = (const float*)d_in[7];
  const float* ebih_b = (const float*)d_in[8];
  const float* ebhh_b = (const float*)d_in[9];
  const float* dWih   = (const float*)d_in[10];
  const float* dWhh   = (const float*)d_in[11];
  const float* dbih   = (const float*)d_in[12];
  const float* dbhh   = (const float*)d_in[13];
  const float* Watt   = (const float*)d_in[14];
  const float* batt   = (const float*)d_in[15];
  const float* Wout   = (const float*)d_in[16];
  const float* bout   = (const float*)d_in[17];

  float* ws = (float*)d_ws;
  bf16_t* GI    = (bf16_t*)d_ws;
  float* enc2   = ws + OFF_ENC2;
  float* scores = ws + OFF_SCORES;
  float* ctx    = ws + OFF_CTX;
  float* gictx  = ws + OFF_GICTX;
  u64* pub      = (u64*)(ws + OFF_PUB);
  u64* pub_f = pub;            // [2][1024]
  u64* pub_b = pub + 2048;     // [2][1024]
  u64* hpub  = pub + 4096;     // [2][1024]
  u64* lpub  = pub + 6144;     // [2][2048]
  float* out = (float*)d_out;

  k_init<<<10, 1024, 0, stream>>>(h0, pub);
  k_gemm_gi<<<dim3(128, 96), 256, 0, stream>>>(x, eWih_f, eWih_b, ebih_f, ebih_b, GI);
  k_recurrence<<<256, 1024, 0, stream>>>(GI, eWhh_f, eWhh_b, ebhh_f, ebhh_b, enc2, pub_f, pub_b);
  k_scores<<<2048, 256, 0, stream>>>(enc2, Watt, batt, scores);
  k_softmax<<<1, 256, 0, stream>>>(scores);
  k_context<<<8, 256, 0, stream>>>(scores, enc2, ctx);
  k_gictx<<<768, 256, 0, stream>>>(dWih, dbih, ctx, gictx);
  k_decinit<<<1, 1024, 0, stream>>>(pub_b, hpub);
  k_decoder<<<128, 1024, 0, stream>>>(gictx, dWih, dWhh, dbhh, Wout, bout, hpub, lpub, out);
}

// Round 8
// 21949.202 us; speedup vs baseline: 1.5595x; 1.5595x over previous
//
#include <hip/hip_runtime.h>
#include <hip/hip_bf16.h>

// ============================================================================
// Seq2seq: bi-GRU encoder (T=8192, H=I=1024) + attention decoder (L=64).
// Inputs/outputs are fp32 (proven: passed reading fp32, absmax 0.0625).
//  - gi = x@Wih.T batched into one GEMM (8192x1024 @ 1024x6144), bf16 scratch.
//  - attention softmax shift-invariance => attn/context constant across all 64
//    decoder steps; computed once.
//  - recurrence sync: each h element is published as an 8B atomic word
//    [epoch32|fp32]; arrival is one parallel relaxed store, detection is 1
//    word/thread polled (s_sleep(1) spin) for epoch==t. Double-buffered by
//    parity; all-to-all reads each step make exact-match polling race-free
//    (writer at most 2 steps ahead).
//  - THIS CONFIG IS THE MEASURED OPTIMUM (r0 = 2.50us/step). The full design
//    space was probed and every perturbation regressed:
//      r1 pack+backoff +0.15us/step (latency-bound, not BW-bound);
//      r3 128B line striding +1.3us/step (line-granular fetch inflation);
//      r4/r5 XCD-local L2 publish/poll: no visibility (sc0 semantics) ->
//        timeout; abandoned;
//      r6 pipelined hot poll +0.23us/step (dangling speculative load drained
//        by the barrier's vmcnt(0) = +1 MALL RTT);
//      r7 register-Whh +1.36us/step (destroyed single-wave coalesced publish:
//        8 serialized line-RMWs at the MALL + sector-granular enc2 writes,
//        WRITE_SIZE 196->590MB).
//    The 2.5us/step is the agent-scope all-to-all RTT through the MALL
//    (per-XCD L2s are not cross-coherent -> no cheaper coherence point),
//    x 8192 inherently sequential steps. Only retained delta vs r0: __expf
//    gates in the encoder tail (harness-validated in r6, absmax unchanged).
// ============================================================================
typedef __hip_bfloat16 bf16_t;
typedef unsigned long long u64;
struct alignas(8) bh4 { bf16_t v[4]; };
__device__ __forceinline__ float bf2f(bf16_t v) { return __bfloat162float(v); }

// workspace offsets (floats); total ~168 MB (proven in-bounds)
static constexpr size_t OFF_ENC2   = 25165824;                 // after bf16 GI
static constexpr size_t OFF_SCORES = OFF_ENC2 + 16777216;
static constexpr size_t OFF_CTX    = OFF_SCORES + 8192;
static constexpr size_t OFF_GICTX  = OFF_CTX + 2048;           // 3072 (+pad)
static constexpr size_t OFF_PUB    = OFF_GICTX + 4096;         // u64 region
// u64 region: pub_f[2][1024] | pub_b[2][1024] | hpub[2][1024] | lpub[2][2048]

static constexpr unsigned TAG_BAD = 0x7FFFFFFFu;

__device__ __forceinline__ u64 pub_load(const u64* p) {
  return __hip_atomic_load(p, __ATOMIC_RELAXED, __HIP_MEMORY_SCOPE_AGENT);
}
__device__ __forceinline__ void pub_store(u64* p, u64 v) {
  __hip_atomic_store(p, v, __ATOMIC_RELAXED, __HIP_MEMORY_SCOPE_AGENT);
}
__device__ __forceinline__ u64 pack(unsigned tag, float f) {
  union { float f; unsigned u; } c; c.f = f;
  return ((u64)tag << 32) | c.u;
}
__device__ __forceinline__ float unpack(u64 w) {
  union { unsigned u; float f; } c; c.u = (unsigned)w;
  return c.f;
}
// fast gate math (few-ulp; error budget dominated by bf16 GI; r6-validated)
__device__ __forceinline__ float fsigmoid(float x) {
  return 1.f / (1.f + __expf(-x));
}
__device__ __forceinline__ float ftanh(float x) {
  float e2 = __expf(2.f * x);
  return 1.f - 2.f / (e2 + 1.f);
}

// ----------------------------------------------------------------------------
__global__ __launch_bounds__(1024) void k_init(const float* __restrict__ h0,
                                               u64* pub) {
  int i = blockIdx.x * 1024 + threadIdx.x;  // grid 10 -> 10240 words
  if (i < 1024)       pub[i] = pack(0u, h0[i]);                 // pub_f[0]
  else if (i < 2048)  pub[i] = pack(TAG_BAD, 0.f);              // pub_f[1]
  else if (i < 3072)  pub[i] = pack(0u, h0[1024 + (i - 2048)]); // pub_b[0]
  else if (i < 10240) pub[i] = pack(TAG_BAD, 0.f);              // rest
}

// ----------------------------------------------------------------------------
// GI = X @ [Wih_f; Wih_b]^T + bias.  64x64 tile, 4x4 microtile, fp32 math,
// bf16 store (scratch only).
// ----------------------------------------------------------------------------
__global__ __launch_bounds__(256) void k_gemm_gi(
    const float* __restrict__ X, const float* __restrict__ Wf,
    const float* __restrict__ Wb, const float* __restrict__ bf,
    const float* __restrict__ bb, bf16_t* __restrict__ GI) {
  __shared__ __align__(16) float As[16][68];
  __shared__ __align__(16) float Bs[16][68];
  const int m0 = blockIdx.x * 64;
  const int n0 = blockIdx.y * 64;
  const int tid = threadIdx.x;
  const int tx = tid & 15, ty = tid >> 4;
  const int lm = tid >> 2, lk = (tid & 3) * 4;
  const float* Wsel = (n0 < 3072) ? Wf : Wb;
  const float* bsel = (n0 < 3072) ? bf : bb;
  const int nadj = (n0 < 3072) ? n0 : (n0 - 3072);
  float acc[4][4];
#pragma unroll
  for (int i = 0; i < 4; ++i)
#pragma unroll
    for (int j = 0; j < 4; ++j) acc[i][j] = 0.f;
  for (int k0 = 0; k0 < 1024; k0 += 16) {
    float4 av = *(const float4*)(X + (size_t)(m0 + lm) * 1024 + k0 + lk);
    float4 bv = *(const float4*)(Wsel + (size_t)(nadj + lm) * 1024 + k0 + lk);
    __syncthreads();
    As[lk + 0][lm] = av.x; As[lk + 1][lm] = av.y; As[lk + 2][lm] = av.z; As[lk + 3][lm] = av.w;
    Bs[lk + 0][lm] = bv.x; Bs[lk + 1][lm] = bv.y; Bs[lk + 2][lm] = bv.z; Bs[lk + 3][lm] = bv.w;
    __syncthreads();
#pragma unroll
    for (int kk = 0; kk < 16; ++kk) {
      float4 a = *(const float4*)&As[kk][ty * 4];
      float4 b = *(const float4*)&Bs[kk][tx * 4];
      acc[0][0] += a.x * b.x; acc[0][1] += a.x * b.y; acc[0][2] += a.x * b.z; acc[0][3] += a.x * b.w;
      acc[1][0] += a.y * b.x; acc[1][1] += a.y * b.y; acc[1][2] += a.y * b.z; acc[1][3] += a.y * b.w;
      acc[2][0] += a.z * b.x; acc[2][1] += a.z * b.y; acc[2][2] += a.z * b.z; acc[2][3] += a.z * b.w;
      acc[3][0] += a.w * b.x; acc[3][1] += a.w * b.y; acc[3][2] += a.w * b.z; acc[3][3] += a.w * b.w;
    }
  }
  float b0 = bsel[nadj + tx * 4 + 0], b1 = bsel[nadj + tx * 4 + 1];
  float b2 = bsel[nadj + tx * 4 + 2], b3 = bsel[nadj + tx * 4 + 3];
#pragma unroll
  for (int i = 0; i < 4; ++i) {
    bh4 o;
    o.v[0] = __float2bfloat16(acc[i][0] + b0);
    o.v[1] = __float2bfloat16(acc[i][1] + b1);
    o.v[2] = __float2bfloat16(acc[i][2] + b2);
    o.v[3] = __float2bfloat16(acc[i][3] + b3);
    *(bh4*)(GI + (size_t)(m0 + ty * 4 + i) * 6144 + n0 + tx * 4) = o;
  }
}

// ----------------------------------------------------------------------------
// Both GRU recurrences. 256 blocks x 1024 thr (1 block/CU, 96 KB Whh in LDS).
// Block owns 8 hidden idx = 24 Whh rows. Wave w: row w (+ row 16+w if w<8).
// Per step: poll 1 word/thread -> LDS h -> dots -> gates (threads 0..7) ->
// publish 8 words (ONE coalesced wave-store). Two __syncthreads/step.
// ----------------------------------------------------------------------------
__global__ __launch_bounds__(1024, 1) void k_recurrence(
    const bf16_t* __restrict__ GI, const float* __restrict__ Whh_f,
    const float* __restrict__ Whh_b, const float* __restrict__ bhh_f,
    const float* __restrict__ bhh_b, float* __restrict__ enc2,
    u64* pub_f, u64* pub_b) {
  __shared__ __align__(16) float w[24][1024];   // 96 KB
  __shared__ __align__(16) float hsh[1024];
  __shared__ float rowsum[24];
  __shared__ float bsh[24];
  __shared__ float gish[24];
  const int blk = blockIdx.x;      // 0..255
  const int dir = blk >> 7;        // 128 blocks/direction
  const int bb = blk & 127;
  const int j0 = bb * 8;
  const int tid = threadIdx.x;
  const int wv = tid >> 6, lane = tid & 63;
  const float* Whh = dir ? Whh_b : Whh_f;
  const float* bhh = dir ? bhh_b : bhh_f;
  u64* pub = dir ? pub_b : pub_f;

  for (int i = tid; i < 24 * 256; i += 1024) {   // stage 24 rows (6 float4/thr)
    int r = i >> 8, c4 = i & 255;
    int g = r >> 3, jj = r & 7;
    *(float4*)&w[r][c4 * 4] =
        *(const float4*)(Whh + (size_t)(g * 1024 + j0 + jj) * 1024 + c4 * 4);
  }
  if (tid < 24) {
    int g = tid >> 3, jj = tid & 7;
    bsh[tid] = bhh[g * 1024 + j0 + jj];
  }
  float gpre = 0.f;
  size_t gcol = 0;
  if (tid < 24) {
    int g = tid >> 3, jj = tid & 7;
    gcol = (size_t)(dir ? 3072 : 0) + g * 1024 + j0 + jj;
    gpre = bf2f(GI[(size_t)(dir ? 8191 : 0) * 6144 + gcol]);
  }
  __syncthreads();

  for (int t = 0; t < 8192; ++t) {
    {  // poll h (word tid) for epoch t; data arrives in the word
      u64* src = pub + (size_t)(t & 1) * 1024 + tid;
      u64 wd = pub_load(src);
      while ((unsigned)(wd >> 32) != (unsigned)t) {
        __builtin_amdgcn_s_sleep(1);
        wd = pub_load(src);
      }
      hsh[tid] = unpack(wd);
    }
    __syncthreads();                 // sync#1: h staged; prior-step gates done
    if (tid < 24) {
      gish[tid] = gpre;
      if (t < 8191) {                // prefetch next gi during this step
        size_t row = dir ? (size_t)(8190 - t) : (size_t)(t + 1);
        gpre = bf2f(GI[row * 6144 + gcol]);
      }
    }
    float a0 = 0.f, a1 = 0.f;
    {
      const float4* hp = (const float4*)hsh;
      const float4* w0 = (const float4*)&w[wv][0];
#pragma unroll
      for (int q = 0; q < 4; ++q) {
        int idx = lane + 64 * q;
        float4 hv = hp[idx], x0 = w0[idx];
        a0 += hv.x * x0.x + hv.y * x0.y + hv.z * x0.z + hv.w * x0.w;
      }
      if (wv < 8) {
        const float4* w1 = (const float4*)&w[16 + wv][0];
#pragma unroll
        for (int q = 0; q < 4; ++q) {
          int idx = lane + 64 * q;
          float4 hv = hp[idx], x1 = w1[idx];
          a1 += hv.x * x1.x + hv.y * x1.y + hv.z * x1.z + hv.w * x1.w;
        }
      }
    }
#pragma unroll
    for (int off = 32; off; off >>= 1) {
      a0 += __shfl_xor(a0, off);
      a1 += __shfl_xor(a1, off);
    }
    if (lane == 0) {
      rowsum[wv] = a0;
      if (wv < 8) rowsum[16 + wv] = a1;
    }
    __syncthreads();                 // sync#2: rowsums ready
    if (tid < 8) {
      int jj = tid, j = j0 + jj;
      float hr = rowsum[jj] + bsh[jj];
      float hz = rowsum[8 + jj] + bsh[8 + jj];
      float hn = rowsum[16 + jj] + bsh[16 + jj];
      float ir = gish[jj], iz = gish[8 + jj], inn = gish[16 + jj];
      float rr = fsigmoid(ir + hr);
      float zz = fsigmoid(iz + hz);
      float nn = ftanh(inn + rr * hn);
      float hnew = (1.f - zz) * nn + zz * hsh[j];
      pub_store(pub + (size_t)((t + 1) & 1) * 1024 + j, pack((unsigned)(t + 1), hnew));
      size_t trow = dir ? (size_t)(8191 - t) : (size_t)t;
      enc2[trow * 2048 + dir * 1024 + j] = hnew;
    }
    // no end-of-loop sync needed: next poll's hsh/gish/rowsum writes are
    // ordered behind sync#1/#2 of step t+1, which require this step's gates.
  }
}

// ----------------------------------------------------------------------------
__global__ __launch_bounds__(256) void k_scores(const float* __restrict__ enc2,
                                                const float* __restrict__ Watt,
                                                const float* __restrict__ batt,
                                                float* __restrict__ scores) {
  int wv = threadIdx.x >> 6, lane = threadIdx.x & 63;
  int t = blockIdx.x * 4 + wv;  // grid 2048
  const float* We = Watt + 1024;
  float a = 0.f;
#pragma unroll
  for (int k = 0; k < 8; ++k) {
    float4 e = *(const float4*)(enc2 + (size_t)t * 2048 + lane * 4 + k * 256);
    float4 ww = *(const float4*)(We + lane * 4 + k * 256);
    a += e.x * ww.x + e.y * ww.y + e.z * ww.z + e.w * ww.w;
  }
#pragma unroll
  for (int off = 32; off; off >>= 1) a += __shfl_xor(a, off);
  if (lane == 0) scores[t] = a + batt[0];
}

__global__ __launch_bounds__(256) void k_softmax(float* __restrict__ s) {
  __shared__ float red[8];
  int tid = threadIdx.x, wv = tid >> 6, lane = tid & 63;
  float m = -1e30f;
  for (int i = tid; i < 8192; i += 256) m = fmaxf(m, s[i]);
#pragma unroll
  for (int off = 32; off; off >>= 1) m = fmaxf(m, __shfl_xor(m, off));
  if (lane == 0) red[wv] = m;
  __syncthreads();
  m = fmaxf(fmaxf(red[0], red[1]), fmaxf(red[2], red[3]));
  float sum = 0.f;
  for (int i = tid; i < 8192; i += 256) sum += expf(s[i] - m);
#pragma unroll
  for (int off = 32; off; off >>= 1) sum += __shfl_xor(sum, off);
  if (lane == 0) red[4 + wv] = sum;
  __syncthreads();
  sum = red[4] + red[5] + red[6] + red[7];
  float inv = 1.0f / sum;
  for (int i = tid; i < 8192; i += 256) s[i] = expf(s[i] - m) * inv;
}

__global__ __launch_bounds__(256) void k_context(const float* __restrict__ attn,
                                                 const float* __restrict__ enc2,
                                                 float* __restrict__ ctx) {
  int k = blockIdx.x * 256 + threadIdx.x;  // grid 8
  float a0 = 0.f, a1 = 0.f, a2 = 0.f, a3 = 0.f;
  for (int t = 0; t < 8192; t += 4) {
    a0 += attn[t] * enc2[(size_t)t * 2048 + k];
    a1 += attn[t + 1] * enc2[(size_t)(t + 1) * 2048 + k];
    a2 += attn[t + 2] * enc2[(size_t)(t + 2) * 2048 + k];
    a3 += attn[t + 3] * enc2[(size_t)(t + 3) * 2048 + k];
  }
  ctx[k] = (a0 + a1) + (a2 + a3);
}

__global__ __launch_bounds__(256) void k_gictx(const float* __restrict__ dWih,
                                               const float* __restrict__ dbih,
                                               const float* __restrict__ ctx,
                                               float* __restrict__ gictx) {
  int wv = threadIdx.x >> 6, lane = threadIdx.x & 63;
  int i = blockIdx.x * 4 + wv;  // grid 768 -> 3072
  float a = 0.f;
#pragma unroll
  for (int k = 0; k < 8; ++k) {
    float4 ww = *(const float4*)(dWih + (size_t)i * 4096 + 2048 + lane * 4 + k * 256);
    float4 c = *(const float4*)(ctx + lane * 4 + k * 256);
    a += ww.x * c.x + ww.y * c.y + ww.z * c.z + ww.w * c.w;
  }
#pragma unroll
  for (int off = 32; off; off >>= 1) a += __shfl_xor(a, off);
  if (lane == 0) gictx[i] = a + dbih[i];
}

// seed decoder h state (tag 0) from bwd final h (tag 8192, parity 0)
__global__ void k_decinit(const u64* __restrict__ pub_b, u64* hpub) {
  int i = threadIdx.x;  // 1x1024
  hpub[i] = pack(0u, unpack(pub_b[i]));
}

// ----------------------------------------------------------------------------
// Decoder: 64 steps, 128 blocks x 1024 thr. Block owns 8 hidden + 16 out rows.
// Phase A: poll h(tag s) + logits(tag s) -> local log-softmax (redundant,
//   deterministic) -> out for step s-1 -> GRU gates -> publish h(tag s+1).
// Phase B: poll h(tag s+1) -> 16 logit rows -> publish logits(tag s+1).
// Final: poll logits(tag 64) -> out for step 63.
// ----------------------------------------------------------------------------
__global__ __launch_bounds__(1024, 1) void k_decoder(
    const float* __restrict__ gictx, const float* __restrict__ dWih,
    const float* __restrict__ dWhh, const float* __restrict__ dbhh,
    const float* __restrict__ Wout, const float* __restrict__ bout,
    u64* hpub, u64* lpub, float* __restrict__ out) {
  __shared__ __align__(16) float hsh[1024];
  __shared__ __align__(16) float lsh[2048];
  __shared__ __align__(16) float dsh[2048];
  __shared__ float rsA[24], rsB[24];
  __shared__ float red[32];
  __shared__ float gctx[24], bsh[24], bo[16];
  const int bb = blockIdx.x;           // 128 blocks
  const int j0 = bb * 8, o0 = bb * 16;
  const int tid = threadIdx.x, wv = tid >> 6, lane = tid & 63;
  if (tid < 24) {
    int g = tid >> 3, jj = tid & 7;
    gctx[tid] = gictx[g * 1024 + j0 + jj];
    bsh[tid] = dbhh[g * 1024 + j0 + jj];
  }
  if (tid < 16) bo[tid] = bout[o0 + tid];
  __syncthreads();

  for (int s = 0; s < 64; ++s) {
    {  // poll h state (tag s)
      u64* hp = hpub + (size_t)(s & 1) * 1024 + tid;
      u64 wd = pub_load(hp);
      while ((unsigned)(wd >> 32) != (unsigned)s) {
        __builtin_amdgcn_s_sleep(1);
        wd = pub_load(hp);
      }
      hsh[tid] = unpack(wd);
    }
    if (s > 0) {  // poll logits (tag s)
      u64* lp = lpub + (size_t)(s & 1) * 2048;
#pragma unroll
      for (int q = 0; q < 2; ++q) {
        int i = tid + q * 1024;
        u64 wd = pub_load(lp + i);
        while ((unsigned)(wd >> 32) != (unsigned)s) {
          __builtin_amdgcn_s_sleep(1);
          wd = pub_load(lp + i);
        }
        lsh[i] = unpack(wd);
      }
    }
    __syncthreads();
    if (s > 0) {  // log-softmax over lsh (redundant per block, deterministic)
      float m = fmaxf(lsh[tid], lsh[tid + 1024]);
#pragma unroll
      for (int off = 32; off; off >>= 1) m = fmaxf(m, __shfl_xor(m, off));
      if (lane == 0) red[wv] = m;
      __syncthreads();
      m = -1e30f;
      for (int i = 0; i < 16; ++i) m = fmaxf(m, red[i]);
      float e = expf(lsh[tid] - m) + expf(lsh[tid + 1024] - m);
#pragma unroll
      for (int off = 32; off; off >>= 1) e += __shfl_xor(e, off);
      if (lane == 0) red[16 + wv] = e;
      __syncthreads();
      float se = 0.f;
      for (int i = 0; i < 16; ++i) se += red[16 + i];
      float c = m + logf(se);
      dsh[tid] = lsh[tid] - c;
      dsh[tid + 1024] = lsh[tid + 1024] - c;
    } else {
      dsh[tid] = 0.f;
      dsh[tid + 1024] = 0.f;
    }
    __syncthreads();
    if (s > 0 && tid < 16) out[(size_t)(s - 1) * 2048 + o0 + tid] = dsh[o0 + tid];
    // gate dots: combo r = g*8+jj; wave wv -> combo wv (+16+wv if wv<8)
    float aA0 = 0.f, aB0 = 0.f, aA1 = 0.f, aB1 = 0.f;
    {
      int g = wv >> 3, jj = wv & 7;
      const float4* rowI = (const float4*)(dWih + (size_t)(g * 1024 + j0 + jj) * 4096);
      const float4* rowH = (const float4*)(dWhh + (size_t)(g * 1024 + j0 + jj) * 1024);
      const float4* dp = (const float4*)dsh;
      const float4* hp = (const float4*)hsh;
#pragma unroll
      for (int q = 0; q < 8; ++q) {
        int idx = lane + 64 * q;
        float4 d = dp[idx], wi = rowI[idx];
        aA0 += d.x * wi.x + d.y * wi.y + d.z * wi.z + d.w * wi.w;
      }
#pragma unroll
      for (int q = 0; q < 4; ++q) {
        int idx = lane + 64 * q;
        float4 h = hp[idx], wh = rowH[idx];
        aB0 += h.x * wh.x + h.y * wh.y + h.z * wh.z + h.w * wh.w;
      }
      if (wv < 8) {
        const float4* rowI2 = (const float4*)(dWih + (size_t)(2 * 1024 + j0 + wv) * 4096);
        const float4* rowH2 = (const float4*)(dWhh + (size_t)(2 * 1024 + j0 + wv) * 1024);
#pragma unroll
        for (int q = 0; q < 8; ++q) {
          int idx = lane + 64 * q;
          float4 d = dp[idx], wi = rowI2[idx];
          aA1 += d.x * wi.x + d.y * wi.y + d.z * wi.z + d.w * wi.w;
        }
#pragma unroll
        for (int q = 0; q < 4; ++q) {
          int idx = lane + 64 * q;
          float4 h = hp[idx], wh = rowH2[idx];
          aB1 += h.x * wh.x + h.y * wh.y + h.z * wh.z + h.w * wh.w;
        }
      }
    }
#pragma unroll
    for (int off = 32; off; off >>= 1) {
      aA0 += __shfl_xor(aA0, off); aB0 += __shfl_xor(aB0, off);
      aA1 += __shfl_xor(aA1, off); aB1 += __shfl_xor(aB1, off);
    }
    if (lane == 0) {
      rsA[wv] = aA0; rsB[wv] = aB0;
      if (wv < 8) { rsA[16 + wv] = aA1; rsB[16 + wv] = aB1; }
    }
    __syncthreads();
    if (tid < 8) {
      int jj = tid, j = j0 + jj;
      float ir = gctx[jj] + rsA[jj];
      float iz = gctx[8 + jj] + rsA[8 + jj];
      float inn = gctx[16 + jj] + rsA[16 + jj];
      float hr = rsB[jj] + bsh[jj];
      float hz = rsB[8 + jj] + bsh[8 + jj];
      float hn = rsB[16 + jj] + bsh[16 + jj];
      float rr = 1.f / (1.f + expf(-(ir + hr)));
      float zz = 1.f / (1.f + expf(-(iz + hz)));
      float nn = tanhf(inn + rr * hn);
      float hnew = (1.f - zz) * nn + zz * hsh[j];
      pub_store(hpub + (size_t)((s + 1) & 1) * 1024 + j, pack((unsigned)(s + 1), hnew));
    }
    __syncthreads();
    {  // phase B: poll h(tag s+1), compute 16 logit rows, publish
      u64* hp = hpub + (size_t)((s + 1) & 1) * 1024 + tid;
      u64 wd = pub_load(hp);
      while ((unsigned)(wd >> 32) != (unsigned)(s + 1)) {
        __builtin_amdgcn_s_sleep(1);
        wd = pub_load(hp);
      }
      hsh[tid] = unpack(wd);
    }
    __syncthreads();
    {
      int o = o0 + wv;
      const float4* rowO = (const float4*)(Wout + (size_t)o * 1024);
      const float4* hp = (const float4*)hsh;
      float l = 0.f;
#pragma unroll
      for (int q = 0; q < 4; ++q) {
        int idx = lane + 64 * q;
        float4 h = hp[idx], wo = rowO[idx];
        l += h.x * wo.x + h.y * wo.y + h.z * wo.z + h.w * wo.w;
      }
#pragma unroll
      for (int off = 32; off; off >>= 1) l += __shfl_xor(l, off);
      if (lane == 0)
        pub_store(lpub + (size_t)((s + 1) & 1) * 2048 + o, pack((unsigned)(s + 1), l + bo[wv]));
    }
    __syncthreads();
  }
  {  // final: logits tag 64 (parity 0) -> out step 63
    u64* lp = lpub + 0;
#pragma unroll
    for (int q = 0; q < 2; ++q) {
      int i = tid + q * 1024;
      u64 wd = pub_load(lp + i);
      while ((unsigned)(wd >> 32) != 64u) {
        __builtin_amdgcn_s_sleep(1);
        wd = pub_load(lp + i);
      }
      lsh[i] = unpack(wd);
    }
  }
  __syncthreads();
  float m = fmaxf(lsh[tid], lsh[tid + 1024]);
#pragma unroll
  for (int off = 32; off; off >>= 1) m = fmaxf(m, __shfl_xor(m, off));
  if (lane == 0) red[wv] = m;
  __syncthreads();
  m = -1e30f;
  for (int i = 0; i < 16; ++i) m = fmaxf(m, red[i]);
  float e = expf(lsh[tid] - m) + expf(lsh[tid + 1024] - m);
#pragma unroll
  for (int off = 32; off; off >>= 1) e += __shfl_xor(e, off);
  if (lane == 0) red[16 + wv] = e;
  __syncthreads();
  float se = 0.f;
  for (int i = 0; i < 16; ++i) se += red[16 + i];
  float c = m + logf(se);
  if (tid < 16) out[(size_t)63 * 2048 + o0 + tid] = lsh[o0 + tid] - c;
}

// ----------------------------------------------------------------------------
extern "C" void kernel_launch(void* const* d_in, const int* in_sizes, int n_in,
                              void* d_out, int out_size, void* d_ws, size_t ws_size,
                              hipStream_t stream) {
  (void)in_sizes; (void)n_in; (void)out_size; (void)ws_size;
  const float* x      = (const float*)d_in[0];
  const float* h0     = (const float*)d_in[1];
  const float* eWih_f = (const float*)d_in[2];
  const float* eWhh_f = (const float*)d_in[3];
  const float* ebih_f = (const float*)d_in[4];
  const float* ebhh_f = (const float*)d_in[5];
  const float* eWih_b = (const float*)d_in[6];
  const float* eWhh_b = (const float*)d_in[7];
  const float* ebih_b = (const float*)d_in[8];
  const float* ebhh_b = (const float*)d_in[9];
  const float* dWih   = (const float*)d_in[10];
  const float* dWhh   = (const float*)d_in[11];
  const float* dbih   = (const float*)d_in[12];
  const float* dbhh   = (const float*)d_in[13];
  const float* Watt   = (const float*)d_in[14];
  const float* batt   = (const float*)d_in[15];
  const float* Wout   = (const float*)d_in[16];
  const float* bout   = (const float*)d_in[17];

  float* ws = (float*)d_ws;
  bf16_t* GI    = (bf16_t*)d_ws;
  float* enc2   = ws + OFF_ENC2;
  float* scores = ws + OFF_SCORES;
  float* ctx    = ws + OFF_CTX;
  float* gictx  = ws + OFF_GICTX;
  u64* pub      = (u64*)(ws + OFF_PUB);
  u64* pub_f = pub;            // [2][1024]
  u64* pub_b = pub + 2048;     // [2][1024]
  u64* hpub  = pub + 4096;     // [2][1024]
  u64* lpub  = pub + 6144;     // [2][2048]
  float* out = (float*)d_out;

  k_init<<<10, 1024, 0, stream>>>(h0, pub);
  k_gemm_gi<<<dim3(128, 96), 256, 0, stream>>>(x, eWih_f, eWih_b, ebih_f, ebih_b, GI);
  k_recurrence<<<256, 1024, 0, stream>>>(GI, eWhh_f, eWhh_b, ebhh_f, ebhh_b, enc2, pub_f, pub_b);
  k_scores<<<2048, 256, 0, stream>>>(enc2, Watt, batt, scores);
  k_softmax<<<1, 256, 0, stream>>>(scores);
  k_context<<<8, 256, 0, stream>>>(scores, enc2, ctx);
  k_gictx<<<768, 256, 0, stream>>>(dWih, dbih, ctx, gictx);
  k_decinit<<<1, 1024, 0, stream>>>(pub_b, hpub);
  k_decoder<<<128, 1024, 0, stream>>>(gictx, dWih, dWhh, dbhh, Wout, bout, hpub, lpub, out);
}